// Round 5
// baseline (235.034 us; speedup 1.0000x reference)
//
#include <hip/hip_runtime.h>
#include <math.h>

// Problem: output [B=2, C=8, H=128, W=128, D=128] fp32.
// t = (x > 0.5 ? x : 0); per (b,c): s = sum t, sy = sum t*(y/H), sx = sum t*(x/W),
// sz = sum t*(z/D); centroids = weighted / s; 8 relations -> scalar loss.
// Memory-bound: 134 MB single-pass read; input is LLC-resident after the
// harness's restore copy, so plain (cached) loads — NOT non-temporal.
//
// R5 = R4 with nt loads reverted to plain float4 loads (single variable).
// Fused single dispatch retained: blocks publish partials via device-scope
// atomicExch + magic flag; last block (63,15) spins on 1024 flags (all blocks
// co-resident: 4096 waves of 8192 capacity), then computes centroids + loss.

#define SLICES 16
#define SLICE_ELEMS (128*128*128)
#define BLOCKS_PER_SLICE 64
#define THREADS 256
#define NBLOCKS (SLICES * BLOCKS_PER_SLICE)    // 1024
#define STRIDE (BLOCKS_PER_SLICE * THREADS)    // 16384 -> exactly 32 iters/thread
#define FLAG_MAGIC 0x13579BDFu

// ws layout (floats): [0..1023]=s, [1024..2047]=sy, [2048..3071]=sx,
// [3072..4095]=sz, then 1024 u32 flags at [4096..5119]. slot = slice*64+blk.

__global__ __launch_bounds__(THREADS)
void gsl_fused(const float* __restrict__ in, float* __restrict__ ws,
               float* __restrict__ out) {
    const int blk   = blockIdx.x;      // 0..63
    const int slice = blockIdx.y;      // 0..15
    const int slot  = slice * BLOCKS_PER_SLICE + blk;
    const int tid   = threadIdx.x;

    unsigned int* flags = reinterpret_cast<unsigned int*>(ws + 4 * NBLOCKS);

    const float4* p = reinterpret_cast<const float4*>(in + (size_t)slice * SLICE_ELEMS);
    const int base = blk * THREADS + tid;

    float s = 0.0f, sy = 0.0f, sx = 0.0f, sz = 0.0f;

    #pragma unroll 8
    for (int i = 0; i < 32; ++i) {
        const int v = base + i * STRIDE;
        float4 f = p[v];                           // cached load: LLC-resident input
        const int e = v << 2;                      // element index of f.x
        float t0 = f.x > 0.5f ? f.x : 0.0f;
        float t1 = f.y > 0.5f ? f.y : 0.0f;
        float t2 = f.z > 0.5f ? f.z : 0.0f;
        float t3 = f.w > 0.5f ? f.w : 0.0f;
        float ts = (t0 + t1) + (t2 + t3);
        float zz = (float)(e & 127);               // z fastest
        float xx = (float)((e >> 7) & 127);
        float yy = (float)(e >> 14);
        s  += ts;
        sy += ts * yy;
        sx += ts * xx;
        sz += ts * zz + (t1 + 2.0f * t2 + 3.0f * t3);
    }

    const float inv = 1.0f / 128.0f;               // H=W=D=128
    sy *= inv; sx *= inv; sz *= inv;

    #pragma unroll
    for (int off = 32; off > 0; off >>= 1) {
        s  += __shfl_down(s,  off, 64);
        sy += __shfl_down(sy, off, 64);
        sx += __shfl_down(sx, off, 64);
        sz += __shfl_down(sz, off, 64);
    }

    __shared__ float4 sh[4];
    const int wave = tid >> 6;
    const int lane = tid & 63;
    if (lane == 0) sh[wave] = make_float4(s, sy, sx, sz);
    __syncthreads();

    if (tid == 0) {
        float4 a = sh[0], b = sh[1], c = sh[2], d = sh[3];
        float ps  = (a.x + b.x) + (c.x + d.x);
        float psy = (a.y + b.y) + (c.y + d.y);
        float psx = (a.z + b.z) + (c.z + d.z);
        float psz = (a.w + b.w) + (c.w + d.w);
        // publish through device-coherent atomics (ws is poison-filled, and
        // per-XCD L2s are not cross-coherent for plain stores)
        atomicExch(&ws[0 * NBLOCKS + slot], ps);
        atomicExch(&ws[1 * NBLOCKS + slot], psy);
        atomicExch(&ws[2 * NBLOCKS + slot], psx);
        atomicExch(&ws[3 * NBLOCKS + slot], psz);
        __threadfence();
        atomicExch(&flags[slot], FLAG_MAGIC);
    }

    // ---- fused finalize: last block spins, then reduces 1024 partials ----
    if (blk != BLOCKS_PER_SLICE - 1 || slice != SLICES - 1) return;

    // each of 256 threads polls 4 flags
    {
        bool done = false;
        while (!done) {
            done = true;
            #pragma unroll
            for (int i = 0; i < 4; ++i) {
                if (atomicAdd(&flags[tid * 4 + i], 0u) != FLAG_MAGIC) { done = false; }
            }
        }
    }
    __threadfence();
    __syncthreads();

    // thread t: slice fs = t>>4, covers 4 consecutive partial slots
    const int fs = tid >> 4;
    const int chunk = tid & 15;
    float rs = 0.0f, rsy = 0.0f, rsx = 0.0f, rsz = 0.0f;
    #pragma unroll
    for (int i = 0; i < 4; ++i) {
        const int sl = fs * BLOCKS_PER_SLICE + chunk * 4 + i;
        rs  += atomicAdd(&ws[0 * NBLOCKS + sl], 0.0f);
        rsy += atomicAdd(&ws[1 * NBLOCKS + sl], 0.0f);
        rsx += atomicAdd(&ws[2 * NBLOCKS + sl], 0.0f);
        rsz += atomicAdd(&ws[3 * NBLOCKS + sl], 0.0f);
    }
    #pragma unroll
    for (int off = 8; off > 0; off >>= 1) {
        rs  += __shfl_down(rs,  off, 16);
        rsy += __shfl_down(rsy, off, 16);
        rsx += __shfl_down(rsx, off, 16);
        rsz += __shfl_down(rsz, off, 16);
    }

    __shared__ float cy[SLICES], cx[SLICES], cz[SLICES];
    if (chunk == 0) {
        cy[fs] = rsy / rs;
        cx[fs] = rsx / rs;
        cz[fs] = rsz / rs;
    }
    __syncthreads();

    if (tid == 0) {
        const int   ri[8] = {0, 1, 2, 3, 4, 5, 6, 0};
        const int   rj[8] = {1, 2, 3, 4, 5, 6, 7, 7};
        const float gy[8] = { 0.1f, 0.0f, -0.1f, 0.0f,  0.05f, 0.0f, 0.1f, -0.05f};
        const float gx[8] = { 0.0f, 0.1f,  0.05f, 0.0f, -0.05f, 0.1f, 0.0f,  0.05f};
        const float gz[8] = { 0.05f, 0.0f, 0.0f,  0.1f,  0.0f, -0.1f, 0.0f,  0.05f};

        float loss = 0.0f;
        #pragma unroll
        for (int r = 0; r < 8; ++r) {
            #pragma unroll
            for (int b = 0; b < 2; ++b) {
                int i = b * 8 + ri[r];
                int j = b * 8 + rj[r];
                float dy = cy[i] - cy[j] - gy[r];
                float dx = cx[i] - cx[j] - gx[r];
                float dz = cz[i] - cz[j] - gz[r];
                if (!isfinite(dy)) dy = 0.0f;
                if (!isfinite(dx)) dx = 0.0f;
                if (!isfinite(dz)) dz = 0.0f;
                loss += 0.5f * (dy * dy + dx * dx + dz * dz);  // mean over B=2
            }
        }
        out[0] = loss;
    }
}

extern "C" void kernel_launch(void* const* d_in, const int* in_sizes, int n_in,
                              void* d_out, int out_size, void* d_ws, size_t ws_size,
                              hipStream_t stream) {
    const float* in = (const float*)d_in[0];
    float* out = (float*)d_out;
    float* ws = (float*)d_ws;   // 4*1024 floats partials + 1024 u32 flags

    gsl_fused<<<dim3(BLOCKS_PER_SLICE, SLICES), THREADS, 0, stream>>>(in, ws, out);
}

// Round 6
// 188.880 us; speedup vs baseline: 1.2444x; 1.2444x over previous
//
#include <hip/hip_runtime.h>
#include <math.h>

// Problem: output [B=2, C=8, H=128, W=128, D=128] fp32.
// t = (x > 0.5 ? x : 0); per (b,c): s = sum t, sy = sum t*(y/H), sx = sum t*(x/W),
// sz = sum t*(z/D); centroids = weighted / s; 8 relations -> scalar loss.
// Memory-bound: 134 MB single-pass read -> ~21 us floor @ 6.3 TB/s.
//
// R6 vs R5 (post-mortem: fused spin cost ~30us; VGPR=32 showed only ~2 loads
// in flight -> latency-bound at 1.8 TB/s):
//  - back to TWO kernels, plain float4 partial stores (kernel boundary = sync)
//  - explicit 8-wide batch-load phase (float4 f[8]) to force 8 outstanding
//    global_load_dwordx4 per thread
//  - 2048 blocks (8/CU, 32 waves/CU = 100% occupancy at low VGPR)
//  - each block streams a CONTIGUOUS 64 KB region (4 KB per iteration)

#define SLICES 16
#define SLICE_ELEMS (128*128*128)
#define BLOCKS_PER_SLICE 128
#define THREADS 256
#define VEC_PER_SLICE (SLICE_ELEMS / 4)                     // 524288
#define VEC_PER_BLOCK (VEC_PER_SLICE / BLOCKS_PER_SLICE)    // 4096 (64 KB)
#define ITERS (VEC_PER_BLOCK / THREADS)                     // 16 = 2 batches of 8
#define NBLOCKS (SLICES * BLOCKS_PER_SLICE)                 // 2048

__global__ __launch_bounds__(THREADS)
void gsl_reduce(const float* __restrict__ in, float4* __restrict__ ws4) {
    const int blk   = blockIdx.x;      // 0..127
    const int slice = blockIdx.y;      // 0..15
    const int tid   = threadIdx.x;

    const float4* p = reinterpret_cast<const float4*>(in + (size_t)slice * SLICE_ELEMS);
    const int blockBase = blk * VEC_PER_BLOCK;   // contiguous 4096-float4 region

    float s = 0.0f, sy = 0.0f, sx = 0.0f, sz = 0.0f;

    #pragma unroll
    for (int batch = 0; batch < ITERS / 8; ++batch) {
        // phase 1: 8 independent loads, all issued before any use
        float4 f[8];
        int v[8];
        #pragma unroll
        for (int j = 0; j < 8; ++j) {
            v[j] = blockBase + (batch * 8 + j) * THREADS + tid;
            f[j] = p[v[j]];
        }
        // phase 2: consume
        #pragma unroll
        for (int j = 0; j < 8; ++j) {
            const int e = v[j] << 2;               // element index of f[j].x
            float t0 = f[j].x > 0.5f ? f[j].x : 0.0f;
            float t1 = f[j].y > 0.5f ? f[j].y : 0.0f;
            float t2 = f[j].z > 0.5f ? f[j].z : 0.0f;
            float t3 = f[j].w > 0.5f ? f[j].w : 0.0f;
            float ts = (t0 + t1) + (t2 + t3);
            float zz = (float)(e & 127);           // z fastest
            float xx = (float)((e >> 7) & 127);
            float yy = (float)(e >> 14);
            s  += ts;
            sy += ts * yy;
            sx += ts * xx;
            sz += ts * zz + (t1 + 2.0f * t2 + 3.0f * t3);
        }
    }

    const float inv = 1.0f / 128.0f;               // H=W=D=128
    sy *= inv; sx *= inv; sz *= inv;

    #pragma unroll
    for (int off = 32; off > 0; off >>= 1) {
        s  += __shfl_down(s,  off, 64);
        sy += __shfl_down(sy, off, 64);
        sx += __shfl_down(sx, off, 64);
        sz += __shfl_down(sz, off, 64);
    }

    __shared__ float4 sh[4];
    const int wave = tid >> 6;
    const int lane = tid & 63;
    if (lane == 0) sh[wave] = make_float4(s, sy, sx, sz);
    __syncthreads();
    if (tid == 0) {
        float4 a = sh[0], b = sh[1], c = sh[2], d = sh[3];
        ws4[slice * BLOCKS_PER_SLICE + blk] =
            make_float4((a.x + b.x) + (c.x + d.x),
                        (a.y + b.y) + (c.y + d.y),
                        (a.z + b.z) + (c.z + d.z),
                        (a.w + b.w) + (c.w + d.w));
    }
}

__global__ __launch_bounds__(THREADS)
void gsl_finalize(const float4* __restrict__ ws4, float* __restrict__ out) {
    const int t = threadIdx.x;
    const int slice = t >> 4;   // 0..15
    const int chunk = t & 15;   // 0..15, each covers 8 block-partials

    float s = 0.0f, sy = 0.0f, sx = 0.0f, sz = 0.0f;
    #pragma unroll
    for (int i = 0; i < 8; ++i) {
        float4 f = ws4[slice * BLOCKS_PER_SLICE + chunk * 8 + i];
        s += f.x; sy += f.y; sx += f.z; sz += f.w;
    }
    #pragma unroll
    for (int off = 8; off > 0; off >>= 1) {
        s  += __shfl_down(s,  off, 16);
        sy += __shfl_down(sy, off, 16);
        sx += __shfl_down(sx, off, 16);
        sz += __shfl_down(sz, off, 16);
    }

    __shared__ float cy[SLICES], cx[SLICES], cz[SLICES];
    if (chunk == 0) {
        cy[slice] = sy / s;
        cx[slice] = sx / s;
        cz[slice] = sz / s;
    }
    __syncthreads();

    if (t == 0) {
        const int   ri[8] = {0, 1, 2, 3, 4, 5, 6, 0};
        const int   rj[8] = {1, 2, 3, 4, 5, 6, 7, 7};
        const float gy[8] = { 0.1f, 0.0f, -0.1f, 0.0f,  0.05f, 0.0f, 0.1f, -0.05f};
        const float gx[8] = { 0.0f, 0.1f,  0.05f, 0.0f, -0.05f, 0.1f, 0.0f,  0.05f};
        const float gz[8] = { 0.05f, 0.0f, 0.0f,  0.1f,  0.0f, -0.1f, 0.0f,  0.05f};

        float loss = 0.0f;
        #pragma unroll
        for (int r = 0; r < 8; ++r) {
            #pragma unroll
            for (int b = 0; b < 2; ++b) {
                int i = b * 8 + ri[r];
                int j = b * 8 + rj[r];
                float dy = cy[i] - cy[j] - gy[r];
                float dx = cx[i] - cx[j] - gx[r];
                float dz = cz[i] - cz[j] - gz[r];
                if (!isfinite(dy)) dy = 0.0f;
                if (!isfinite(dx)) dx = 0.0f;
                if (!isfinite(dz)) dz = 0.0f;
                loss += 0.5f * (dy * dy + dx * dx + dz * dz);  // mean over B=2
            }
        }
        out[0] = loss;
    }
}

extern "C" void kernel_launch(void* const* d_in, const int* in_sizes, int n_in,
                              void* d_out, int out_size, void* d_ws, size_t ws_size,
                              hipStream_t stream) {
    const float* in = (const float*)d_in[0];
    float* out = (float*)d_out;
    float4* ws4 = (float4*)d_ws;   // 2048 float4 partials: [slice][block]

    gsl_reduce<<<dim3(BLOCKS_PER_SLICE, SLICES), THREADS, 0, stream>>>(in, ws4);
    gsl_finalize<<<1, THREADS, 0, stream>>>(ws4, out);
}

// Round 7
// 177.337 us; speedup vs baseline: 1.3254x; 1.0651x over previous
//
#include <hip/hip_runtime.h>
#include <math.h>

// Problem: output [B=2, C=8, H=128, W=128, D=128] fp32.
// t = (x > 0.5 ? x : 0); per (b,c): s = sum t, sy = sum t*(y/H), sx = sum t*(x/W),
// sz = sum t*(z/D); centroids = weighted / s; 8 relations -> scalar loss.
//
// R7 vs R6 (post-mortem: R4-vs-R5 A/B shows nt loads were +15us FASTER; R5 PMC
// shows HBM reads at 640 GB/s = scattered 64B hit/miss interleave after the
// 512 MiB ws-poison evicted half the input from LLC):
//  - nt (non-temporal) float4 loads: stream past L2, avoid hit/miss interleave
//  - 16-deep explicit load batch (entire per-thread work) issued before any
//    consumption; __launch_bounds__(256,2) grants ~256 VGPR budget so the
//    compiler keeps the batch live (R5's VGPR=32 proved collapse to ~2-deep)
//  - two kernels, plain partial stores (kernel boundary = coherence)

#define SLICES 16
#define SLICE_ELEMS (128*128*128)
#define BLOCKS_PER_SLICE 128
#define THREADS 256
#define VEC_PER_SLICE (SLICE_ELEMS / 4)                     // 524288
#define VEC_PER_BLOCK (VEC_PER_SLICE / BLOCKS_PER_SLICE)    // 4096 (64 KB)
#define DEPTH 16                                            // loads in flight/thread

typedef float floatx4 __attribute__((ext_vector_type(4)));

__global__ __launch_bounds__(THREADS, 2)
void gsl_reduce(const float* __restrict__ in, float4* __restrict__ ws4) {
    const int blk   = blockIdx.x;      // 0..127
    const int slice = blockIdx.y;      // 0..15
    const int tid   = threadIdx.x;

    const floatx4* p = reinterpret_cast<const floatx4*>(in + (size_t)slice * SLICE_ELEMS);
    const int base = blk * VEC_PER_BLOCK + tid;   // 16 loads at base + j*256

    // phase 1: issue all 16 independent nt loads
    floatx4 f[DEPTH];
    #pragma unroll
    for (int j = 0; j < DEPTH; ++j) {
        f[j] = __builtin_nontemporal_load(&p[base + j * THREADS]);
    }

    // phase 2: consume
    float s = 0.0f, sy = 0.0f, sx = 0.0f, sz = 0.0f;
    #pragma unroll
    for (int j = 0; j < DEPTH; ++j) {
        const int v = base + j * THREADS;
        const int e = v << 2;                      // element index of f[j].x
        float t0 = f[j].x > 0.5f ? f[j].x : 0.0f;
        float t1 = f[j].y > 0.5f ? f[j].y : 0.0f;
        float t2 = f[j].z > 0.5f ? f[j].z : 0.0f;
        float t3 = f[j].w > 0.5f ? f[j].w : 0.0f;
        float ts = (t0 + t1) + (t2 + t3);
        float zz = (float)(e & 127);               // z fastest
        float xx = (float)((e >> 7) & 127);
        float yy = (float)(e >> 14);
        s  += ts;
        sy += ts * yy;
        sx += ts * xx;
        sz += ts * zz + (t1 + 2.0f * t2 + 3.0f * t3);
    }

    const float inv = 1.0f / 128.0f;               // H=W=D=128
    sy *= inv; sx *= inv; sz *= inv;

    #pragma unroll
    for (int off = 32; off > 0; off >>= 1) {
        s  += __shfl_down(s,  off, 64);
        sy += __shfl_down(sy, off, 64);
        sx += __shfl_down(sx, off, 64);
        sz += __shfl_down(sz, off, 64);
    }

    __shared__ float4 sh[4];
    const int wave = tid >> 6;
    const int lane = tid & 63;
    if (lane == 0) sh[wave] = make_float4(s, sy, sx, sz);
    __syncthreads();
    if (tid == 0) {
        float4 a = sh[0], b = sh[1], c = sh[2], d = sh[3];
        ws4[slice * BLOCKS_PER_SLICE + blk] =
            make_float4((a.x + b.x) + (c.x + d.x),
                        (a.y + b.y) + (c.y + d.y),
                        (a.z + b.z) + (c.z + d.z),
                        (a.w + b.w) + (c.w + d.w));
    }
}

__global__ __launch_bounds__(THREADS)
void gsl_finalize(const float4* __restrict__ ws4, float* __restrict__ out) {
    const int t = threadIdx.x;
    const int slice = t >> 4;   // 0..15
    const int chunk = t & 15;   // 0..15, each covers 8 block-partials

    float s = 0.0f, sy = 0.0f, sx = 0.0f, sz = 0.0f;
    #pragma unroll
    for (int i = 0; i < 8; ++i) {
        float4 f = ws4[slice * BLOCKS_PER_SLICE + chunk * 8 + i];
        s += f.x; sy += f.y; sx += f.z; sz += f.w;
    }
    #pragma unroll
    for (int off = 8; off > 0; off >>= 1) {
        s  += __shfl_down(s,  off, 16);
        sy += __shfl_down(sy, off, 16);
        sx += __shfl_down(sx, off, 16);
        sz += __shfl_down(sz, off, 16);
    }

    __shared__ float cy[SLICES], cx[SLICES], cz[SLICES];
    if (chunk == 0) {
        cy[slice] = sy / s;
        cx[slice] = sx / s;
        cz[slice] = sz / s;
    }
    __syncthreads();

    if (t == 0) {
        const int   ri[8] = {0, 1, 2, 3, 4, 5, 6, 0};
        const int   rj[8] = {1, 2, 3, 4, 5, 6, 7, 7};
        const float gy[8] = { 0.1f, 0.0f, -0.1f, 0.0f,  0.05f, 0.0f, 0.1f, -0.05f};
        const float gx[8] = { 0.0f, 0.1f,  0.05f, 0.0f, -0.05f, 0.1f, 0.0f,  0.05f};
        const float gz[8] = { 0.05f, 0.0f, 0.0f,  0.1f,  0.0f, -0.1f, 0.0f,  0.05f};

        float loss = 0.0f;
        #pragma unroll
        for (int r = 0; r < 8; ++r) {
            #pragma unroll
            for (int b = 0; b < 2; ++b) {
                int i = b * 8 + ri[r];
                int j = b * 8 + rj[r];
                float dy = cy[i] - cy[j] - gy[r];
                float dx = cx[i] - cx[j] - gx[r];
                float dz = cz[i] - cz[j] - gz[r];
                if (!isfinite(dy)) dy = 0.0f;
                if (!isfinite(dx)) dx = 0.0f;
                if (!isfinite(dz)) dz = 0.0f;
                loss += 0.5f * (dy * dy + dx * dx + dz * dz);  // mean over B=2
            }
        }
        out[0] = loss;
    }
}

extern "C" void kernel_launch(void* const* d_in, const int* in_sizes, int n_in,
                              void* d_out, int out_size, void* d_ws, size_t ws_size,
                              hipStream_t stream) {
    const float* in = (const float*)d_in[0];
    float* out = (float*)d_out;
    float4* ws4 = (float4*)d_ws;   // 2048 float4 partials: [slice][block]

    gsl_reduce<<<dim3(BLOCKS_PER_SLICE, SLICES), THREADS, 0, stream>>>(in, ws4);
    gsl_finalize<<<1, THREADS, 0, stream>>>(ws4, out);
}